// Round 4
// baseline (195.051 us; speedup 1.0000x reference)
//
#include <hip/hip_runtime.h>

// LRN_19705309954750 — cross-channel banded LRN on [B=64, C=128, H=56, W=56] fp32.
// y[c] = sum_{d=-8..8} x[(c+d)%128]^2 ; out = x * (y*ALPHA/17 + 1)^(-0.75)
//
// R3 post-mortem: zero-halo version got hbm_bytes to 180 MB but only 6.1
// waves/CU -> latency-bound at 2.45 TB/s (occupancy 14%). This version trades
// a little halo (NSEG=2, 1.27x reads, mostly L3-absorbed) for 4x the waves:
// scalar float columns x 2 channel segments = 6272 waves = 24.5 waves/CU.

#define B_DIM 64
#define C_DIM 128
#define HW_DIM (56 * 56)        // 3136
#define NCOL (B_DIM * HW_DIM)   // 200704 scalar columns
#define NSEG 2
#define SEGC (C_DIM / NSEG)     // 64 channels per thread

__device__ __forceinline__ float pow_m075(float t) {
    // t in [1, ~1.01]; HW log2 + exp2 (~1 ulp each) — far inside 0.108 absmax
    return __builtin_amdgcn_exp2f(-0.75f * __builtin_amdgcn_logf(t));
}

__global__ __launch_bounds__(128) void lrn_kernel(const float* __restrict__ x,
                                                  float* __restrict__ out) {
    const float kAlphaOverR = 0.001f / 17.0f;

    const int col = blockIdx.x * 128 + threadIdx.x;   // [0, NCOL)
    const int b   = col / HW_DIM;
    const int hw  = col - b * HW_DIM;
    const int c0  = blockIdx.y * SEGC;                // segment start channel

    const float* base = x + ((size_t)b * C_DIM) * HW_DIM + hw;  // channel stride = HW
    float* obase      = out + ((size_t)b * C_DIM) * HW_DIM + hw;

    // Init window sum for c = c0: channels (c0-8 .. c0+8) mod 128
    float s = 0.f;
#pragma unroll
    for (int d = -8; d <= 8; ++d) {
        const int ch = (c0 + d + C_DIM) & (C_DIM - 1);
        const float v = base[(size_t)ch * HW_DIM];
        s += v * v;
    }

#pragma unroll 8
    for (int i = 0; i < SEGC; ++i) {
        const int c = c0 + i;                         // [c0, c0+63], no mod needed
        const float xc = base[(size_t)c * HW_DIM];    // L1/L2 hit (fetched 9 iters ago)

        obase[(size_t)c * HW_DIM] = xc * pow_m075(fmaf(s, kAlphaOverR, 1.0f));

        // Slide: add channel (c+9), drop (c-8), both mod 128
        const int ci = (c + 9) & (C_DIM - 1);
        const int co = (c - 8 + C_DIM) & (C_DIM - 1);
        const float vin  = base[(size_t)ci * HW_DIM];
        const float vout = base[(size_t)co * HW_DIM];
        s += vin * vin - vout * vout;
    }
}

extern "C" void kernel_launch(void* const* d_in, const int* in_sizes, int n_in,
                              void* d_out, int out_size, void* d_ws, size_t ws_size,
                              hipStream_t stream) {
    const float* x = (const float*)d_in[0];   // [64,128,56,56] fp32
    // d_in[1] (inhiMat) is a constant circulant band — computed analytically, unused.
    float* out = (float*)d_out;

    // NCOL/128 = 1568 blocks in x, 2 channel segments in y:
    // 3136 blocks of 128 threads = 6272 waves = 24.5 waves/CU.
    dim3 grid(NCOL / 128, NSEG);
    lrn_kernel<<<grid, 128, 0, stream>>>(x, out);
}

// Round 5
// 187.640 us; speedup vs baseline: 1.0395x; 1.0395x over previous
//
#include <hip/hip_runtime.h>

// LRN_19705309954750 — cross-channel banded LRN on [B=64, C=128, H=56, W=56] fp32.
// y[c] = sum_{d=-8..8} x[(c+d)%128]^2 ; out = x * (y*ALPHA/17 + 1)^(-0.75)
//
// R4 post-mortem: occupancy 48%, hbm_bytes near-ideal (209 MB), but BW stuck
// at 2.9 TB/s with VGPR_Count=28 — loads can't stay in flight; latency-bound.
// R5: register ring of the last 17 channel planes (fully unrolled, static
// indices). Each channel = exactly 1 load + 1 store; the fresh load's ring
// slot was last read 17 iterations ago, so loads hoist far ahead of the
// serial window-sum chain. Shape kept from R4 (NSEG=2, float2, L3-absorbed
// halo): 3136 waves = 12.25/CU, 64-thread blocks.

#define B_DIM 64
#define C_DIM 128
#define HW_DIM (56 * 56)        // 3136
#define HW2 (HW_DIM / 2)        // 1568 float2 columns per plane
#define NCOL2 (B_DIM * HW2)     // 100352 float2 columns
#define NSEG 2
#define SEGC (C_DIM / NSEG)     // 64 channels per thread
#define RING 17

__device__ __forceinline__ float pow_m075(float t) {
    // t in [1, ~1.01]; HW log2 + exp2 (~1 ulp each) — far inside 0.108 absmax
    return __builtin_amdgcn_exp2f(-0.75f * __builtin_amdgcn_logf(t));
}

__global__ __launch_bounds__(64) void lrn_kernel(const float2* __restrict__ x,
                                                 float2* __restrict__ out) {
    const float kAlphaOverR = 0.001f / 17.0f;

    const int col = blockIdx.x * 64 + threadIdx.x;   // [0, NCOL2)
    const int b   = col / HW2;
    const int hw2 = col - b * HW2;
    const int c0  = blockIdx.y * SEGC;

    const float2* base = x + ((size_t)b * C_DIM) * HW2 + hw2;   // chan stride = HW2
    float2* obase      = out + ((size_t)b * C_DIM) * HW2 + hw2;

    // Ring r[d] holds channel (c0 - 8 + d) for d = 0..16; load once, sum once.
    float2 r[RING];
#pragma unroll
    for (int d = 0; d < RING; ++d) {
        const int ch = (c0 + d - 8 + C_DIM) & (C_DIM - 1);
        r[d] = base[(size_t)ch * HW2];
    }
    float sx = 0.f, sy = 0.f;
#pragma unroll
    for (int d = 0; d < RING; ++d) {
        sx += r[d].x * r[d].x;
        sy += r[d].y * r[d].y;
    }

    // Fully unrolled so ring indices are compile-time registers.
#pragma unroll
    for (int i = 0; i < SEGC; ++i) {
        const int c = c0 + i;
        const int slot_out = i % RING;          // holds channel c-8 (window out)
        const int slot_x   = (i + 8) % RING;    // holds channel c   (numerator)
        const int ch_in    = (c + 9) & (C_DIM - 1);

        const float2 vin = base[(size_t)ch_in * HW2];   // the ONLY load this iter

        const float2 xc = r[slot_x];
        float2 o;
        o.x = xc.x * pow_m075(fmaf(sx, kAlphaOverR, 1.0f));
        o.y = xc.y * pow_m075(fmaf(sy, kAlphaOverR, 1.0f));
        obase[(size_t)c * HW2] = o;

        const float2 vout = r[slot_out];
        sx += vin.x * vin.x - vout.x * vout.x;
        sy += vin.y * vin.y - vout.y * vout.y;
        r[slot_out] = vin;                      // vin becomes ring resident
    }
}

extern "C" void kernel_launch(void* const* d_in, const int* in_sizes, int n_in,
                              void* d_out, int out_size, void* d_ws, size_t ws_size,
                              hipStream_t stream) {
    const float2* x = (const float2*)d_in[0];   // [64,128,56,56] fp32
    // d_in[1] (inhiMat) is a constant circulant band — computed analytically, unused.
    float2* out = (float2*)d_out;

    // 1568 blocks x 2 segments, 64-thread (1-wave) blocks:
    // 3136 waves = 12.25 waves/CU, fine-grained balance.
    dim3 grid(NCOL2 / 64, NSEG);
    lrn_kernel<<<grid, 64, 0, stream>>>(x, out);
}